// Round 5
// baseline (381.175 us; speedup 1.0000x reference)
//
#include <hip/hip_runtime.h>

#define NN 512
#define CC 1024
#define OO 256
#define VV 68
#define PP 7
#define NC (NN*CC)
#define NV_CNT 34816.0f   // N*T*V = 512*68

__device__ __forceinline__ int part_of(int v){
  return (v>=17)+(v>=22)+(v>=27)+(v>=36)+(v>=42)+(v>=48);
}

// K0: repack w1 [o][c] -> w1p[cb][o] (float4 units), coalesced read.
// Block 0 also zeroes the 4-copy BN atomic accumulator (8192 floats).
__global__ __launch_bounds__(256) void k0_prep(const float* __restrict__ w1,
    float* __restrict__ w1p, float* __restrict__ accum){
  int g = blockIdx.x*256 + threadIdx.x;          // f4 idx in w1: g = o*256+cb
  int o = g >> 8, cb = g & 255;
  float4 v = ((const float4*)w1)[g];
  ((float4*)w1p)[cb*256 + o] = v;
  if (blockIdx.x == 0){
    float4 z = make_float4(0.f,0.f,0.f,0.f);
    #pragma unroll
    for (int i=0;i<8;i++)
      ((float4*)accum)[i*256 + threadIdx.x] = z;  // 2048 f4 = 8192 floats
  }
}

// K12: one block per n. Fuses part-sum (S into LDS, S2 into regs), the
// o x c GEMM (from LDS, wave-uniform 2-addr broadcasts), softmax, and the
// BN partial contribution (4-copy global fp32 atomics).
__global__ __launch_bounds__(256) void k12_att(const float* __restrict__ x,
    const float* __restrict__ w1p, const float* __restrict__ b1,
    const float* __restrict__ w2, const float* __restrict__ b2,
    float* __restrict__ att, float* __restrict__ accum){
  int n = blockIdx.x;
  int t = threadIdx.x;

  __shared__ float sS[PP*1024];                  // 28672 B: S[p][c] for this n
  __shared__ float hred[8*256];                  // 8192 B: ch-reduction scratch
  __shared__ float red_s[4][PP], red_m[4][PP], pre[PP], att_s[PP];

  // ---- Phase A: part sums over V for rows c = j*256+t (S->LDS, S2->regs)
  float qreg[4][PP];
  #pragma unroll
  for (int j=0;j<4;j++){
    int c = j*256 + t;
    const float4* xr = (const float4*)(x + ((size_t)n*CC + c)*VV);
    float s[PP];
    #pragma unroll
    for (int p=0;p<PP;p++){ s[p]=0.f; qreg[j][p]=0.f; }
    #pragma unroll
    for (int i=0;i<17;i++){
      float4 v4 = xr[i];
      #pragma unroll
      for (int jj=0;jj<4;jj++){
        int p = part_of(i*4+jj);                 // folds to constant
        float e = (jj==0)?v4.x:(jj==1)?v4.y:(jj==2)?v4.z:v4.w;
        s[p] += e;
        qreg[j][p] = fmaf(e, e, qreg[j][p]);
      }
    }
    #pragma unroll
    for (int p=0;p<PP;p++) sS[p*1024 + c] = s[p]; // bank = c%32, conflict-free
  }
  __syncthreads();

  // ---- Phase B: GEMM  acc[k][p] = sum_{c in ch-slice} S[c,p]*w1[o=k*32+oh,c]
  int oh = t & 31, ch = t >> 5;
  float acc[8][PP];
  #pragma unroll
  for (int k=0;k<8;k++)
    #pragma unroll
    for (int p=0;p<PP;p++) acc[k][p] = 0.f;

  const float4* wp  = (const float4*)w1p;
  const float4* sf4 = (const float4*)sS;         // [p*256 + cb]
  for (int i=0;i<32;i++){
    int gcb = ch*32 + i;
    const float4* wrow = wp + (size_t)gcb*256 + oh;
    float4 w[8];
    #pragma unroll
    for (int k=0;k<8;k++) w[k] = wrow[32*k];
    #pragma unroll
    for (int p=0;p<PP;p++){
      float4 sv = sf4[p*256 + gcb];              // 2 addrs/wave: free broadcast
      #pragma unroll
      for (int k=0;k<8;k++){
        acc[k][p] = fmaf(w[k].x, sv.x, acc[k][p]);
        acc[k][p] = fmaf(w[k].y, sv.y, acc[k][p]);
        acc[k][p] = fmaf(w[k].z, sv.z, acc[k][p]);
        acc[k][p] = fmaf(w[k].w, sv.w, acc[k][p]);
      }
    }
  }

  // ---- Phase C: reduce over ch, mean/max over o, softmax over p
  const float inv_cnt[PP] = {1.f/17.f,1.f/5.f,1.f/5.f,1.f/9.f,1.f/6.f,1.f/6.f,1.f/20.f};
  float bo = b1[t];
  float h[PP];
  #pragma unroll
  for (int p=0;p<PP;p++){
    __syncthreads();
    #pragma unroll
    for (int k=0;k<8;k++) hred[ch*256 + k*32 + oh] = acc[k][p];
    __syncthreads();
    float hs = 0.f;
    #pragma unroll
    for (int c8=0;c8<8;c8++) hs += hred[c8*256 + t];
    h[p] = fmaf(hs, inv_cnt[p], bo);
  }

  int lane = t & 63, wid = t >> 6;
  #pragma unroll
  for (int p=0;p<PP;p++){
    float sm = h[p], mx = h[p];
    #pragma unroll
    for (int off=32; off>0; off>>=1){
      sm += __shfl_down(sm, off, 64);
      mx = fmaxf(mx, __shfl_down(mx, off, 64));
    }
    if (lane==0){ red_s[wid][p]=sm; red_m[wid][p]=mx; }
  }
  __syncthreads();
  if (t < PP){
    int p = t;
    float sm = red_s[0][p]+red_s[1][p]+red_s[2][p]+red_s[3][p];
    float mx = fmaxf(fmaxf(red_m[0][p],red_m[1][p]),
                     fmaxf(red_m[2][p],red_m[3][p]));
    pre[p] = w2[0]*(sm*(1.f/(float)OO)) + w2[1]*mx + b2[0];
  }
  __syncthreads();
  if (t == 0){
    float m = pre[0];
    #pragma unroll
    for (int p=1;p<PP;p++) m = fmaxf(m, pre[p]);
    float e[PP], sum=0.f;
    #pragma unroll
    for (int p=0;p<PP;p++){ e[p] = expf(pre[p]-m); sum += e[p]; }
    float inv = 1.f/sum;
    #pragma unroll
    for (int p=0;p<PP;p++){
      float a = e[p]*inv;
      att_s[p] = a;
      att[n*PP+p] = a;
    }
  }
  __syncthreads();

  // ---- Phase D: BN contribution for this n (S from LDS, S2 from regs)
  float a[PP], a2[PP];
  #pragma unroll
  for (int p=0;p<PP;p++){ a[p] = att_s[p]; a2[p] = a[p]*a[p]; }
  float* acc_sm = accum + (n & 3)*2048;          // 4 copies cut contention 4x
  float* acc_sq = acc_sm + 1024;
  #pragma unroll
  for (int j=0;j<4;j++){
    int c = j*256 + t;
    float sm=0.f, sq=0.f;
    #pragma unroll
    for (int p=0;p<PP;p++){
      sm = fmaf(a[p],  sS[p*1024 + c], sm);
      sq = fmaf(a2[p], qreg[j][p],     sq);
    }
    atomicAdd(&acc_sm[c], sm);
    atomicAdd(&acc_sq[c], sq);
  }
}

// K4: out = relu( x*(att_j*sc + 1) + sh ), BN finalize inlined from accum.
__global__ __launch_bounds__(256) void k4_out(const float* __restrict__ x,
    const float* __restrict__ att, const float* __restrict__ accum,
    const float* __restrict__ gamma, const float* __restrict__ beta,
    float* __restrict__ out){
  int f = blockIdx.x*256 + threadIdx.x;          // float4 index, < NC*17
  int n = blockIdx.x / 68;                       // uniform within block
  __shared__ float s_att[PP];
  if (threadIdx.x < PP) s_att[threadIdx.x] = att[n*PP + threadIdx.x];
  __syncthreads();
  int r = f/17;
  int q = f - r*17;
  int v0 = q*4;
  int c = r & (CC-1);
  float4 xv = ((const float4*)x)[f];
  float sm = accum[c]      + accum[2048+c] + accum[4096+c] + accum[6144+c];
  float sq = accum[1024+c] + accum[3072+c] + accum[5120+c] + accum[7168+c];
  float mean = sm * (1.0f/NV_CNT);
  float var  = sq * (1.0f/NV_CNT) - mean*mean;
  float rstd = rsqrtf(var + 1e-5f);
  float sc = gamma[c]*rstd;
  float sh = beta[c] - mean*sc;
  float vals[4];
  #pragma unroll
  for (int j=0;j<4;j++){
    int p = part_of(v0 + j);
    float a = s_att[p];
    float e = (j==0)?xv.x:(j==1)?xv.y:(j==2)?xv.z:xv.w;
    vals[j] = fmaxf(fmaf(e, fmaf(a, sc, 1.0f), sh), 0.0f);
  }
  float4 ov; ov.x=vals[0]; ov.y=vals[1]; ov.z=vals[2]; ov.w=vals[3];
  ((float4*)out)[f] = ov;
}

extern "C" void kernel_launch(void* const* d_in, const int* in_sizes, int n_in,
                              void* d_out, int out_size, void* d_ws, size_t ws_size,
                              hipStream_t stream) {
  const float* x     = (const float*)d_in[0];
  const float* w1    = (const float*)d_in[1];
  const float* b1    = (const float*)d_in[2];
  const float* w2    = (const float*)d_in[3];
  const float* b2    = (const float*)d_in[4];
  const float* gamma = (const float*)d_in[5];
  const float* beta  = (const float*)d_in[6];
  float* out = (float*)d_out;

  float* w1p   = (float*)d_ws;                   // 256*1024 floats (1 MB)
  float* accum = w1p + OO*CC;                    // 4 copies x 2 x 1024 = 8192
  float* att   = accum + 8192;                   // 512*7
  // total ~1.05 MB of ws

  k0_prep <<<256,         256, 0, stream>>>(w1, w1p, accum);
  k12_att <<<NN,          256, 0, stream>>>(x, w1p, b1, w2, b2, att, accum);
  k4_out  <<<(NC*17)/256, 256, 0, stream>>>(x, att, accum, gamma, beta, out);
}

// Round 6
// 344.872 us; speedup vs baseline: 1.1053x; 1.1053x over previous
//
#include <hip/hip_runtime.h>

#define NN 512
#define CC 1024
#define OO 256
#define VV 68
#define PP 7
#define NC (NN*CC)
#define NV_CNT 34816.0f   // N*T*V = 512*68

__device__ __forceinline__ int part_of(int v){
  return (v>=17)+(v>=22)+(v>=27)+(v>=36)+(v>=42)+(v>=48);
}

// K0: repack w1 [o][c] -> w1p[cb][o] (float4 units), coalesced read.
__global__ __launch_bounds__(256) void k0_prep(const float* __restrict__ w1,
    float* __restrict__ w1p){
  int g = blockIdx.x*256 + threadIdx.x;          // f4 idx in w1: g = o*256+cb
  int o = g >> 8, cb = g & 255;
  float4 v = ((const float4*)w1)[g];
  ((float4*)w1p)[cb*256 + o] = v;
}

// K12: one block per n. Phase A: chunked LDS-transpose part-sum (coalesced x
// reads; S->LDS, S2->regs of reducer half-threads). Phase B: o x c GEMM from
// LDS. Phase C: softmax. Phase D: per-block BN partials (NO atomics).
__global__ __launch_bounds__(256) void k12_att(const float* __restrict__ x,
    const float* __restrict__ w1p, const float* __restrict__ b1,
    const float* __restrict__ w2, const float* __restrict__ b2,
    float* __restrict__ att, float* __restrict__ partial){
  int n = blockIdx.x;
  int t = threadIdx.x;

  __shared__ float stg[128*69];                  // 35328 B staging / phase-C scratch
  __shared__ float sS[PP*1024];                  // 28672 B: S[p][c] for this n
  __shared__ float red_s[4][PP], red_m[4][PP], pre[PP], att_s[PP];

  // ---- Phase A: 8 chunks of 128 rows. Coalesced f4 loads -> LDS transpose
  // -> 128 reducer threads produce S (LDS) and S2 (regs q8).
  float q8[8][PP];                               // S2 partials (t<128 meaningful)
  #pragma unroll
  for (int cc=0;cc<8;cc++)
    #pragma unroll
    for (int p=0;p<PP;p++) q8[cc][p]=0.f;

  const float4* x4 = (const float4*)x;
  for (int cc=0; cc<8; cc++){
    int base = n*17408 + cc*2176;
    #pragma unroll
    for (int k=0;k<9;k++){
      int g = k*256 + t;                         // local f4 idx in chunk
      if (k==8 && t>=128) break;
      float4 v = x4[base + g];
      int row = g/17, q = g - row*17;
      float* d = &stg[row*69 + q*4];
      d[0]=v.x; d[1]=v.y; d[2]=v.z; d[3]=v.w;
    }
    __syncthreads();
    if (t < 128){
      const float* r = &stg[t*69];
      int c = cc*128 + t;
      float s[PP];
      #pragma unroll
      for (int p=0;p<PP;p++) s[p]=0.f;
      #pragma unroll
      for (int v=0; v<VV; v++){
        int p = part_of(v);                      // folds to constant
        float e = r[v];
        s[p] += e;
        q8[cc][p] = fmaf(e, e, q8[cc][p]);
      }
      #pragma unroll
      for (int p=0;p<PP;p++) sS[p*1024 + c] = s[p];
    }
    __syncthreads();
  }

  // ---- Phase B: GEMM acc[k][p] = sum_{c in ch-slice} S[c,p]*w1[o=k*32+oh,c]
  int oh = t & 31, ch = t >> 5;
  float acc[8][PP];
  #pragma unroll
  for (int k=0;k<8;k++)
    #pragma unroll
    for (int p=0;p<PP;p++) acc[k][p] = 0.f;

  const float4* wp  = (const float4*)w1p;
  const float4* sf4 = (const float4*)sS;         // [p*256 + cb]
  for (int i=0;i<32;i++){
    int gcb = ch*32 + i;
    const float4* wrow = wp + (size_t)gcb*256 + oh;
    float4 w[8];
    #pragma unroll
    for (int k=0;k<8;k++) w[k] = wrow[32*k];
    #pragma unroll
    for (int p=0;p<PP;p++){
      float4 sv = sf4[p*256 + gcb];              // 2 addrs/wave broadcast
      #pragma unroll
      for (int k=0;k<8;k++){
        acc[k][p] = fmaf(w[k].x, sv.x, acc[k][p]);
        acc[k][p] = fmaf(w[k].y, sv.y, acc[k][p]);
        acc[k][p] = fmaf(w[k].z, sv.z, acc[k][p]);
        acc[k][p] = fmaf(w[k].w, sv.w, acc[k][p]);
      }
    }
  }

  // ---- Phase C: reduce over ch (scratch = stg), mean/max over o, softmax
  const float inv_cnt[PP] = {1.f/17.f,1.f/5.f,1.f/5.f,1.f/9.f,1.f/6.f,1.f/6.f,1.f/20.f};
  float* hred = stg;                             // 2048 floats reused
  float bo = b1[t];
  float h[PP];
  #pragma unroll
  for (int p=0;p<PP;p++){
    __syncthreads();
    #pragma unroll
    for (int k=0;k<8;k++) hred[ch*256 + k*32 + oh] = acc[k][p];
    __syncthreads();
    float hs = 0.f;
    #pragma unroll
    for (int c8=0;c8<8;c8++) hs += hred[c8*256 + t];
    h[p] = fmaf(hs, inv_cnt[p], bo);
  }

  int lane = t & 63, wid = t >> 6;
  #pragma unroll
  for (int p=0;p<PP;p++){
    float sm = h[p], mx = h[p];
    #pragma unroll
    for (int off=32; off>0; off>>=1){
      sm += __shfl_down(sm, off, 64);
      mx = fmaxf(mx, __shfl_down(mx, off, 64));
    }
    if (lane==0){ red_s[wid][p]=sm; red_m[wid][p]=mx; }
  }
  __syncthreads();
  if (t < PP){
    int p = t;
    float sm = red_s[0][p]+red_s[1][p]+red_s[2][p]+red_s[3][p];
    float mx = fmaxf(fmaxf(red_m[0][p],red_m[1][p]),
                     fmaxf(red_m[2][p],red_m[3][p]));
    pre[p] = w2[0]*(sm*(1.f/(float)OO)) + w2[1]*mx + b2[0];
  }
  __syncthreads();
  if (t == 0){
    float m = pre[0];
    #pragma unroll
    for (int p=1;p<PP;p++) m = fmaxf(m, pre[p]);
    float e[PP], sum=0.f;
    #pragma unroll
    for (int p=0;p<PP;p++){ e[p] = expf(pre[p]-m); sum += e[p]; }
    float inv = 1.f/sum;
    #pragma unroll
    for (int p=0;p<PP;p++){
      float a = e[p]*inv;
      att_s[p] = a;
      att[n*PP+p] = a;
    }
  }
  __syncthreads();

  // ---- Phase D: BN partials for this n (S from LDS, S2 from q8 regs).
  // partial[n*2048 + c] = sum_p a*S ; partial[n*2048 + 1024 + c] = sum_p a^2*S2
  if (t < 128){
    float a[PP], a2[PP];
    #pragma unroll
    for (int p=0;p<PP;p++){ a[p] = att_s[p]; a2[p] = a[p]*a[p]; }
    #pragma unroll
    for (int cc=0;cc<8;cc++){
      int c = cc*128 + t;
      float sm=0.f, sq=0.f;
      #pragma unroll
      for (int p=0;p<PP;p++){
        sm = fmaf(a[p],  sS[p*1024 + c], sm);
        sq = fmaf(a2[p], q8[cc][p],      sq);
      }
      partial[n*2048 + c]        = sm;
      partial[n*2048 + 1024 + c] = sq;
    }
  }
}

// K3b1: reduce partials over 64-n chunks. 32 blocks = 8 nch x 4 cb.
__global__ __launch_bounds__(256) void k3b1_reduce(const float* __restrict__ partial,
    float* __restrict__ p2){
  int nch = blockIdx.x >> 2, cb = blockIdx.x & 3;
  int c = cb*256 + threadIdx.x;
  float sm=0.f, sq=0.f;
  for (int i=0;i<64;i++){
    int n = nch*64 + i;
    sm += partial[n*2048 + c];
    sq += partial[n*2048 + 1024 + c];
  }
  p2[nch*2048 + c]        = sm;
  p2[nch*2048 + 1024 + c] = sq;
}

// K3b2: final reduce + BN finalize -> scale/shift per channel.
__global__ __launch_bounds__(256) void k3b2_finalize(const float* __restrict__ p2,
    const float* __restrict__ gamma, const float* __restrict__ beta,
    float* __restrict__ scsh){
  int c = blockIdx.x*256 + threadIdx.x;
  float sm=0.f, sq=0.f;
  #pragma unroll
  for (int ch=0;ch<8;ch++){
    sm += p2[ch*2048 + c];
    sq += p2[ch*2048 + 1024 + c];
  }
  float mean = sm * (1.0f/NV_CNT);
  float var  = sq * (1.0f/NV_CNT) - mean*mean;
  float rstd = rsqrtf(var + 1e-5f);
  float sc = gamma[c]*rstd;
  scsh[c]        = sc;
  scsh[1024 + c] = beta[c] - mean*sc;
}

// K4: out = relu( x*(att_j*sc + 1) + sh ), float4 over flat index.
__global__ __launch_bounds__(256) void k4_out(const float* __restrict__ x,
    const float* __restrict__ att, const float* __restrict__ scsh,
    float* __restrict__ out){
  int f = blockIdx.x*256 + threadIdx.x;          // float4 index, < NC*17
  int n = blockIdx.x / 68;                       // uniform within block
  __shared__ float s_att[PP];
  if (threadIdx.x < PP) s_att[threadIdx.x] = att[n*PP + threadIdx.x];
  __syncthreads();
  int r = f/17;
  int q = f - r*17;
  int v0 = q*4;
  int c = r & (CC-1);
  float4 xv = ((const float4*)x)[f];
  float sc = scsh[c];
  float sh = scsh[1024 + c];
  float vals[4];
  #pragma unroll
  for (int j=0;j<4;j++){
    int p = part_of(v0 + j);
    float a = s_att[p];
    float e = (j==0)?xv.x:(j==1)?xv.y:(j==2)?xv.z:xv.w;
    vals[j] = fmaxf(fmaf(e, fmaf(a, sc, 1.0f), sh), 0.0f);
  }
  float4 ov; ov.x=vals[0]; ov.y=vals[1]; ov.z=vals[2]; ov.w=vals[3];
  ((float4*)out)[f] = ov;
}

extern "C" void kernel_launch(void* const* d_in, const int* in_sizes, int n_in,
                              void* d_out, int out_size, void* d_ws, size_t ws_size,
                              hipStream_t stream) {
  const float* x     = (const float*)d_in[0];
  const float* w1    = (const float*)d_in[1];
  const float* b1    = (const float*)d_in[2];
  const float* w2    = (const float*)d_in[3];
  const float* b2    = (const float*)d_in[4];
  const float* gamma = (const float*)d_in[5];
  const float* beta  = (const float*)d_in[6];
  float* out = (float*)d_out;

  float* w1p     = (float*)d_ws;                 // 256*1024 floats (1 MB)
  float* partial = w1p + OO*CC;                  // 512*2048 floats (4 MB)
  float* p2      = partial + NN*2048;            // 8*2048
  float* scsh    = p2 + 8*2048;                  // 2048
  float* att     = scsh + 2048;                  // 512*7
  // total ~5.1 MB of ws; all buffers fully overwritten every call

  k0_prep      <<<256,         256, 0, stream>>>(w1, w1p);
  k12_att      <<<NN,          256, 0, stream>>>(x, w1p, b1, w2, b2, att, partial);
  k3b1_reduce  <<<32,          256, 0, stream>>>(partial, p2);
  k3b2_finalize<<<4,           256, 0, stream>>>(p2, gamma, beta, scsh);
  k4_out       <<<(NC*17)/256, 256, 0, stream>>>(x, att, scsh, out);
}

// Round 8
// 328.234 us; speedup vs baseline: 1.1613x; 1.0507x over previous
//
#include <hip/hip_runtime.h>

#define NN 512
#define CC 1024
#define OO 256
#define VV 68
#define PP 7
#define NC (NN*CC)
#define NV_CNT 34816.0f   // N*T*V = 512*68

typedef float floatx4 __attribute__((ext_vector_type(4)));

__device__ __forceinline__ int part_of(int v){
  return (v>=17)+(v>=22)+(v>=27)+(v>=36)+(v>=42)+(v>=48);
}

// K0: repack w1 [o][c] -> w1p[cb][o] (float4 units), coalesced read.
__global__ __launch_bounds__(256) void k0_prep(const float* __restrict__ w1,
    float* __restrict__ w1p){
  int g = blockIdx.x*256 + threadIdx.x;          // f4 idx in w1: g = o*256+cb
  int o = g >> 8, cb = g & 255;
  float4 v = ((const float4*)w1)[g];
  ((float4*)w1p)[cb*256 + o] = v;
}

// K1: streaming part-sum. 4096 blocks x 128 rows. Coalesced f4 loads ->
// LDS transpose stg[v][row] (stride 129). 256 threads reduce half-rows
// (34 v each), combine via LDS.
__global__ __launch_bounds__(256) void k1_partsum(const float* __restrict__ x,
    float* __restrict__ S, float* __restrict__ S2){
  __shared__ float stg[68*129];                  // 35088 B; later reused as hs/hq
  int R = blockIdx.x*128;                        // first row of block
  const float4* src = (const float4*)(x + (size_t)R*VV);
  #pragma unroll
  for (int k=0;k<9;k++){
    int g = k*256 + threadIdx.x;                 // f4 idx in [0,2176)
    if (k==8 && threadIdx.x>=128) break;
    float4 v4 = src[g];
    int row = g/17, q = g - row*17;
    stg[(q*4+0)*129 + row] = v4.x;
    stg[(q*4+1)*129 + row] = v4.y;
    stg[(q*4+2)*129 + row] = v4.z;
    stg[(q*4+3)*129 + row] = v4.w;
  }
  __syncthreads();

  int row  = threadIdx.x & 127;
  int half = threadIdx.x >> 7;                   // 0: v<34, 1: v>=34
  float s[PP], q2[PP];
  #pragma unroll
  for (int p=0;p<PP;p++){ s[p]=0.f; q2[p]=0.f; }
  int v0 = half*34;
  #pragma unroll
  for (int i=0;i<34;i++){
    int v = v0 + i;
    int p = part_of(v);                          // folds to constant per half
    float e = stg[v*129 + row];
    s[p] += e;
    q2[p] = fmaf(e, e, q2[p]);
  }
  __syncthreads();                               // stg reads done
  float* hs = stg;                               // reuse: 128*7
  float* hq = stg + 128*PP;                      // 128*7
  if (half==1){
    #pragma unroll
    for (int p=0;p<PP;p++){ hs[row*PP+p]=s[p]; hq[row*PP+p]=q2[p]; }
  }
  __syncthreads();
  if (half==0){
    int r = R + row;
    #pragma unroll
    for (int p=0;p<PP;p++){
      S [p*NC + r] = s[p]  + hs[row*PP+p];
      S2[p*NC + r] = q2[p] + hq[row*PP+p];
    }
  }
}

// K2: per n (512 blocks): stage S row (28KB LDS), o x c GEMM (wave-uniform
// LDS broadcasts, w1p from L2), softmax, BN partials (S from LDS, S2 from
// coalesced global). LDS ~37KB -> 4 blocks/CU, 4 waves/SIMD.
__global__ __launch_bounds__(256) void k2_att(const float* __restrict__ S,
    const float* __restrict__ S2, const float* __restrict__ w1p,
    const float* __restrict__ b1, const float* __restrict__ w2,
    const float* __restrict__ b2, float* __restrict__ att,
    float* __restrict__ partial){
  int n = blockIdx.x;
  int t = threadIdx.x;

  __shared__ float4 sSf4[PP*256];                // 28672 B: S[p][c] this n
  __shared__ float hred[2048];                   // 8192 B
  __shared__ float red_s[4][PP], red_m[4][PP], pre[PP], att_s[PP];
  float* sSl = (float*)sSf4;                     // [p*1024 + c]

  for (int u = t; u < PP*256; u += 256){
    int p = u >> 8, cb = u & 255;
    sSf4[u] = *(const float4*)(S + (size_t)p*NC + (size_t)n*CC + cb*4);
  }
  __syncthreads();

  // GEMM acc[k][p] = sum_{c slice} S[c,p] * w1[o=k*32+oh, c]
  int oh = t & 31, ch = t >> 5;
  float acc[8][PP];
  #pragma unroll
  for (int k=0;k<8;k++)
    #pragma unroll
    for (int p=0;p<PP;p++) acc[k][p] = 0.f;

  const float4* wp = (const float4*)w1p;
  for (int i=0;i<32;i++){
    int gcb = ch*32 + i;
    const float4* wrow = wp + (size_t)gcb*256 + oh;
    float4 w[8];
    #pragma unroll
    for (int k=0;k<8;k++) w[k] = wrow[32*k];
    #pragma unroll
    for (int p=0;p<PP;p++){
      float4 sv = sSf4[p*256 + gcb];             // 2 addrs/wave broadcast
      #pragma unroll
      for (int k=0;k<8;k++){
        acc[k][p] = fmaf(w[k].x, sv.x, acc[k][p]);
        acc[k][p] = fmaf(w[k].y, sv.y, acc[k][p]);
        acc[k][p] = fmaf(w[k].z, sv.z, acc[k][p]);
        acc[k][p] = fmaf(w[k].w, sv.w, acc[k][p]);
      }
    }
  }

  // reduce over ch, mean/max over o, softmax over p
  const float inv_cnt[PP] = {1.f/17.f,1.f/5.f,1.f/5.f,1.f/9.f,1.f/6.f,1.f/6.f,1.f/20.f};
  float bo = b1[t];
  float h[PP];
  #pragma unroll
  for (int p=0;p<PP;p++){
    __syncthreads();
    #pragma unroll
    for (int k=0;k<8;k++) hred[ch*256 + k*32 + oh] = acc[k][p];
    __syncthreads();
    float hs = 0.f;
    #pragma unroll
    for (int c8=0;c8<8;c8++) hs += hred[c8*256 + t];
    h[p] = fmaf(hs, inv_cnt[p], bo);
  }

  int lane = t & 63, wid = t >> 6;
  #pragma unroll
  for (int p=0;p<PP;p++){
    float sm = h[p], mx = h[p];
    #pragma unroll
    for (int off=32; off>0; off>>=1){
      sm += __shfl_down(sm, off, 64);
      mx = fmaxf(mx, __shfl_down(mx, off, 64));
    }
    if (lane==0){ red_s[wid][p]=sm; red_m[wid][p]=mx; }
  }
  __syncthreads();
  if (t < PP){
    int p = t;
    float sm = red_s[0][p]+red_s[1][p]+red_s[2][p]+red_s[3][p];
    float mx = fmaxf(fmaxf(red_m[0][p],red_m[1][p]),
                     fmaxf(red_m[2][p],red_m[3][p]));
    pre[p] = w2[0]*(sm*(1.f/(float)OO)) + w2[1]*mx + b2[0];
  }
  __syncthreads();
  if (t == 0){
    float m = pre[0];
    #pragma unroll
    for (int p=1;p<PP;p++) m = fmaxf(m, pre[p]);
    float e[PP], sum=0.f;
    #pragma unroll
    for (int p=0;p<PP;p++){ e[p] = expf(pre[p]-m); sum += e[p]; }
    float inv = 1.f/sum;
    #pragma unroll
    for (int p=0;p<PP;p++){
      float a = e[p]*inv;
      att_s[p] = a;
      att[n*PP+p] = a;
    }
  }
  __syncthreads();

  // BN partials: sm from LDS S, sq from global S2 (coalesced dword loads)
  float a[PP], a2[PP];
  #pragma unroll
  for (int p=0;p<PP;p++){ a[p] = att_s[p]; a2[p] = a[p]*a[p]; }
  const float* S2n = S2 + (size_t)n*CC;
  #pragma unroll
  for (int j=0;j<4;j++){
    int c = j*256 + t;
    float sm=0.f, sq=0.f;
    #pragma unroll
    for (int p=0;p<PP;p++){
      sm = fmaf(a[p],  sSl[p*1024 + c],   sm);
      sq = fmaf(a2[p], S2n[(size_t)p*NC + c], sq);
    }
    partial[n*2048 + c]        = sm;
    partial[n*2048 + 1024 + c] = sq;
  }
}

// K3b: single-dispatch reduce over n + BN finalize. 32 blocks x 256 thr.
__global__ __launch_bounds__(256) void k3b_finalize(const float* __restrict__ partial,
    const float* __restrict__ gamma, const float* __restrict__ beta,
    float* __restrict__ scsh){
  __shared__ float rs[8][32], rq[8][32];
  int cl = threadIdx.x & 31, grp = threadIdx.x >> 5;
  int c = blockIdx.x*32 + cl;
  float sm=0.f, sq=0.f;
  for (int i=0;i<64;i++){
    int n = grp*64 + i;
    sm += partial[n*2048 + c];
    sq += partial[n*2048 + 1024 + c];
  }
  rs[grp][cl] = sm; rq[grp][cl] = sq;
  __syncthreads();
  if (threadIdx.x < 32){
    float tsm=0.f, tsq=0.f;
    #pragma unroll
    for (int g=0; g<8; g++){ tsm += rs[g][threadIdx.x]; tsq += rq[g][threadIdx.x]; }
    int cc = blockIdx.x*32 + threadIdx.x;
    float mean = tsm * (1.0f/NV_CNT);
    float var  = tsq * (1.0f/NV_CNT) - mean*mean;
    float rstd = rsqrtf(var + 1e-5f);
    float sc = gamma[cc]*rstd;
    scsh[cc]        = sc;
    scsh[1024 + cc] = beta[cc] - mean*sc;
  }
}

// K4: out = relu( x*(att_j*sc + 1) + sh ); nontemporal stores via ext_vector.
__global__ __launch_bounds__(256) void k4_out(const float* __restrict__ x,
    const float* __restrict__ att, const float* __restrict__ scsh,
    float* __restrict__ out){
  int f = blockIdx.x*256 + threadIdx.x;          // float4 index, < NC*17
  int n = blockIdx.x / 68;                       // uniform within block
  __shared__ float s_att[PP];
  if (threadIdx.x < PP) s_att[threadIdx.x] = att[n*PP + threadIdx.x];
  __syncthreads();
  int r = f/17;
  int q = f - r*17;
  int v0 = q*4;
  int c = r & (CC-1);
  float4 xv = ((const float4*)x)[f];
  float sc = scsh[c];
  float sh = scsh[1024 + c];
  float vals[4];
  #pragma unroll
  for (int j=0;j<4;j++){
    int p = part_of(v0 + j);
    float a = s_att[p];
    float e = (j==0)?xv.x:(j==1)?xv.y:(j==2)?xv.z:xv.w;
    vals[j] = fmaxf(fmaf(e, fmaf(a, sc, 1.0f), sh), 0.0f);
  }
  floatx4 ov; ov.x=vals[0]; ov.y=vals[1]; ov.z=vals[2]; ov.w=vals[3];
  __builtin_nontemporal_store(ov, ((floatx4*)out) + f);
}

extern "C" void kernel_launch(void* const* d_in, const int* in_sizes, int n_in,
                              void* d_out, int out_size, void* d_ws, size_t ws_size,
                              hipStream_t stream) {
  const float* x     = (const float*)d_in[0];
  const float* w1    = (const float*)d_in[1];
  const float* b1    = (const float*)d_in[2];
  const float* w2    = (const float*)d_in[3];
  const float* b2    = (const float*)d_in[4];
  const float* gamma = (const float*)d_in[5];
  const float* beta  = (const float*)d_in[6];
  float* out = (float*)d_out;

  float* w1p     = (float*)d_ws;                 // 256*1024 (1 MB)
  float* S       = w1p + OO*CC;                  // 7*NC (14 MB)
  float* S2      = S + 7*NC;                     // 7*NC (14 MB)
  float* partial = S2 + 7*NC;                    // 512*2048 (4 MB)
  float* scsh    = partial + NN*2048;            // 2048
  float* att     = scsh + 2048;                  // 512*7
  // ~33 MB of ws; every buffer fully overwritten each call

  k0_prep     <<<256,         256, 0, stream>>>(w1, w1p);
  k1_partsum  <<<NC/128,      256, 0, stream>>>(x, S, S2);
  k2_att      <<<NN,          256, 0, stream>>>(S, S2, w1p, b1, w2, b2, att, partial);
  k3b_finalize<<<32,          256, 0, stream>>>(partial, gamma, beta, scsh);
  k4_out      <<<(NC*17)/256, 256, 0, stream>>>(x, att, scsh, out);
}